// Round 6
// baseline (2989.548 us; speedup 1.0000x reference)
//
#include <hip/hip_runtime.h>
#include <hip/hip_bf16.h>

// Problem constants
#define B_   32
#define TP_  256
#define TQ_  64
#define D_   256
#define H_   128
#define G4_  512   // 4*H

// ---------- helpers ----------
__device__ __forceinline__ float lanebc(float v, int l) {
  // broadcast lane l of v to all lanes (uniform/literal l)
  return __int_as_float(__builtin_amdgcn_readlane(__float_as_int(v), l));
}
__device__ __forceinline__ float fast_tanh(float x) {
  x = fminf(fmaxf(x, -20.f), 20.f);
  float e = __expf(2.f * x);
  return __fdividef(e - 1.f, e + 1.f);
}
__device__ __forceinline__ float fast_sig(float x) {
  return __fdividef(1.f, 1.f + __expf(-x));
}

// ---------- tiled fp32 GEMM: C[M,N] = A[M,K] @ B[K,N] (+ bias[N]) ----------
// 128x128 tile, BK=8, 256 threads, 8x8 micro-tile.
__global__ __launch_bounds__(256)
void gemm_bias_kernel(const float* __restrict__ A, const float* __restrict__ Bm,
                      const float* __restrict__ bias, float* __restrict__ C,
                      int M, int N, int K)
{
  __shared__ float As[8][132];   // [k][m] transposed, +4 pad
  __shared__ float Bs[8][132];   // [k][n], +4 pad
  const int tid = threadIdx.x;
  const int tx = tid & 15;
  const int ty = tid >> 4;
  const int m0 = blockIdx.x * 128, n0 = blockIdx.y * 128;

  float acc[8][8];
#pragma unroll
  for (int i = 0; i < 8; ++i)
#pragma unroll
    for (int j = 0; j < 8; ++j) acc[i][j] = 0.f;

  const int am = tid >> 1, ak = (tid & 1) * 4;
  const int bk = tid >> 5, bn = (tid & 31) * 4;
  const float* Ap = A + (size_t)(m0 + am) * K + ak;
  const float* Bp = Bm + (size_t)bk * N + n0 + bn;

  for (int kt = 0; kt < K; kt += 8) {
    float4 a4 = *(const float4*)(Ap + kt);
    float4 b4 = *(const float4*)(Bp + (size_t)kt * N);
    __syncthreads();
    As[ak + 0][am] = a4.x; As[ak + 1][am] = a4.y;
    As[ak + 2][am] = a4.z; As[ak + 3][am] = a4.w;
    *(float4*)&Bs[bk][bn] = b4;
    __syncthreads();
#pragma unroll
    for (int k = 0; k < 8; ++k) {
      float4 a0 = *(const float4*)&As[k][ty * 8];
      float4 a1 = *(const float4*)&As[k][ty * 8 + 4];
      float4 b0 = *(const float4*)&Bs[k][tx * 8];
      float4 b1 = *(const float4*)&Bs[k][tx * 8 + 4];
      float av[8] = {a0.x, a0.y, a0.z, a0.w, a1.x, a1.y, a1.z, a1.w};
      float bv[8] = {b0.x, b0.y, b0.z, b0.w, b1.x, b1.y, b1.z, b1.w};
#pragma unroll
      for (int i = 0; i < 8; ++i)
#pragma unroll
        for (int j = 0; j < 8; ++j) acc[i][j] += av[i] * bv[j];
    }
  }

  float bb[8] = {0.f, 0.f, 0.f, 0.f, 0.f, 0.f, 0.f, 0.f};
  if (bias) {
    float4 b0 = *(const float4*)&bias[n0 + tx * 8];
    float4 b1 = *(const float4*)&bias[n0 + tx * 8 + 4];
    bb[0] = b0.x; bb[1] = b0.y; bb[2] = b0.z; bb[3] = b0.w;
    bb[4] = b1.x; bb[5] = b1.y; bb[6] = b1.z; bb[7] = b1.w;
  }
#pragma unroll
  for (int i = 0; i < 8; ++i) {
    float* cp = C + (size_t)(m0 + ty * 8 + i) * N + n0 + tx * 8;
    float4 o0, o1;
    o0.x = acc[i][0] + bb[0]; o0.y = acc[i][1] + bb[1];
    o0.z = acc[i][2] + bb[2]; o0.w = acc[i][3] + bb[3];
    o1.x = acc[i][4] + bb[4]; o1.y = acc[i][5] + bb[5];
    o1.z = acc[i][6] + bb[6]; o1.w = acc[i][7] + bb[7];
    *(float4*)(cp)     = o0;
    *(float4*)(cp + 4) = o1;
  }
}

// ---------- sequential scan: one block per (batch, dir) chain ----------
// 512 threads, __launch_bounds__(512) => 8-wave block, 2 waves/SIMD, VGPR cap 256.
// Pinned/thread: wreg[64] (Wh rows 0-63, own column n) + wpr[32] + qz[64] + gqr[16]
// = 176 VGPR; Wh rows 64-127 in 128KB LDS (XOR-swizzled 16B granules, conflict-free).
// Per-step global traffic: XW row (2KB) + Gpx row (0.5KB) only.
// ROUND-5 LESSON: VGPR_Count=64 meant launch_bounds(1024,4) made the allocator
// spill all pinned arrays to scratch -> same perf as streaming. Verify VGPR_Count
// is 200-256 this round.
__global__ __launch_bounds__(512)
void scan_kernel(const float* __restrict__ Gq,
                 const float* __restrict__ Gpx,
                 const float* __restrict__ XW,   // [2][B*TP*4H]
                 const float* __restrict__ QZ,   // [2][B*TQ*4H]
                 const float* __restrict__ W_pr, // (384,128)
                 const float* __restrict__ Wlf,  // (640,512)
                 const float* __restrict__ Wlb,  // (640,512)
                 const float* __restrict__ w_att,
                 const float* __restrict__ b_match,
                 const float* __restrict__ mask_p,
                 const float* __restrict__ mask_q,
                 float* __restrict__ out)        // states (B,TP,2H) then last (B,2H)
{
  const int tid  = threadIdx.x;
  const int lane = tid & 63;
  const int bch  = blockIdx.x >> 1;
  const int dir  = blockIdx.x & 1;
  const int n    = tid;          // pre column [0,512)   (P4)
  const int j1   = tid & 127;    // gpr column           (P1)
  const int kc   = tid >> 7;     // k-chunk [0,4)        (P1)
  const int t8   = tid >> 3;     // query timestep [0,64)(P2)
  const int k8   = tid & 7;      // j-slice [0,8)        (P2)

  // LDS: 128KB Wh-half + ~6.5KB working = ~134.5KB (< 160KB/CU)
  __shared__ float whlds[64 * 512];   // [n][granule g^(n&15)][4], rows 64..127
  __shared__ float h_s[H_], c_s[H_];
  __shared__ __align__(16) float gpr_s[H_];
  __shared__ float part_s[4][H_];
  __shared__ float a_s[TQ_];
  __shared__ float alpha_s[TQ_];
  __shared__ float pre_s[G4_];
  __shared__ __align__(16) float wa_s[H_];

  const float* Wl   = dir ? Wlb : Wlf;
  const float* XWd  = XW + (size_t)dir * (B_ * TP_ * G4_) + (size_t)bch * TP_ * G4_;
  const float* QZd  = QZ + (size_t)dir * (B_ * TQ_ * G4_) + (size_t)bch * TQ_ * G4_;
  const float* Gqb  = Gq + (size_t)bch * TQ_ * H_;
  const float* Gpxb = Gpx + (size_t)bch * TP_ * H_;
  const float* mpb  = mask_p + bch * TP_;
  const float  bm   = b_match[0];

  // ---- one-time staging ----
  // Wh LDS half: rows 64..127 of own column n. granule g=(k-64)>>2, sub=(k-64)&3,
  // physical slot g^(n&15) (16-lane clock groups cover all 16 slots -> conflict-free).
  for (int k = 0; k < 64; ++k) {
    float v = Wl[(size_t)(512 + 64 + k) * G4_ + n];     // coalesced across tid
    int g = k >> 2, sub = k & 3;
    whlds[(n << 6) + ((g ^ (n & 15)) << 2) + sub] = v;
  }
  // Wh register half: rows 0..63 of column n
  float wreg[64];
#pragma unroll
  for (int i = 0; i < 64; ++i)
    wreg[i] = Wl[(size_t)(512 + i) * G4_ + n];
  // Wpr_h: thread (kc,j1) holds rows kc*32..+32 of column j1
  float wpr[32];
#pragma unroll
  for (int i = 0; i < 32; ++i)
    wpr[i] = W_pr[(size_t)(256 + kc * 32 + i) * H_ + j1];
  // QZ column: qz[t2] = QZ[b,d][t2][n]
  float qz[TQ_];
#pragma unroll
  for (int t2 = 0; t2 < TQ_; ++t2)
    qz[t2] = QZd[(size_t)t2 * G4_ + n];
  // P2 per-thread Gq slice (16 regs); w_att shared via LDS
  float gqr[16];
#pragma unroll
  for (int i = 0; i < 16; ++i)
    gqr[i] = Gqb[t8 * H_ + k8 * 16 + i];
  if (tid < H_) wa_s[tid] = w_att[tid];
  float mqv = 0.f;
  if (tid < TQ_) mqv = mask_q[bch * TQ_ + tid];
  if (tid < H_) { h_s[tid] = 0.f; c_s[tid] = 0.f; }
  __syncthreads();

  const float* whbase = whlds + (size_t)(n << 6);
  const int    nx     = (n & 15);

  for (int s = 0; s < TP_; ++s) {
    const int t = dir ? (TP_ - 1 - s) : s;

    // per-step global prefetch (overlaps phase A)
    float xw_v = XWd[(size_t)t * G4_ + n];
    float gpx_v = 0.f, mp = 0.f;
    if (tid < H_) { gpx_v = Gpxb[t * H_ + tid]; mp = mpb[t]; }

    // stage h for wave broadcast
    float h2  = h_s[lane];
    float h2b = h_s[64 + lane];

    // ---- P1 partial: gpr[j1] over rows kc*32..+32 of Wpr_h ----
    {
      float accp = 0.f;
      float hsrc = (kc >= 2) ? h2b : h2;
      const int hb = (kc & 1) * 32;
#pragma unroll
      for (int i = 0; i < 32; ++i) accp += lanebc(hsrc, hb + i) * wpr[i];
      part_s[kc][j1] = accp;
    }
    // ---- P4h: acc = XW[n] + h @ Wh[:,n] (rows 0..63 regs, 64..127 LDS) ----
    float acc = xw_v;
#pragma unroll
    for (int i = 0; i < 64; ++i) acc += lanebc(h2, i) * wreg[i];
#pragma unroll
    for (int g = 0; g < 16; ++g) {
      const float4 w4 = *(const float4*)(whbase + ((g ^ nx) << 2));
      acc += lanebc(h2b, 4 * g + 0) * w4.x;
      acc += lanebc(h2b, 4 * g + 1) * w4.y;
      acc += lanebc(h2b, 4 * g + 2) * w4.z;
      acc += lanebc(h2b, 4 * g + 3) * w4.w;
    }
    __syncthreads();   // B1: part_s ready

    // ---- gpr combine ----
    if (tid < H_) {
      gpr_s[tid] = gpx_v + part_s[0][tid] + part_s[1][tid]
                 + part_s[2][tid] + part_s[3][tid];
    }
    __syncthreads();   // B2: gpr_s ready

    // ---- P2: a[t8] = bm + sum_j w_att[j]*tanh(gpr[j]+Gq[t8][j]), j=k8*16..+16 ----
    {
      const float4* gp  = (const float4*)&gpr_s[k8 * 16];
      const float4* wp4 = (const float4*)&wa_s[k8 * 16];
      float p = 0.f;
#pragma unroll
      for (int q = 0; q < 4; ++q) {
        const float4 g4 = gp[q];
        const float4 w4 = wp4[q];
        p += w4.x * fast_tanh(g4.x + gqr[q * 4 + 0]);
        p += w4.y * fast_tanh(g4.y + gqr[q * 4 + 1]);
        p += w4.z * fast_tanh(g4.z + gqr[q * 4 + 2]);
        p += w4.w * fast_tanh(g4.w + gqr[q * 4 + 3]);
      }
      p += __shfl_xor(p, 1);
      p += __shfl_xor(p, 2);
      p += __shfl_xor(p, 4);
      if (k8 == 0) a_s[t8] = p + bm;
    }
    __syncthreads();   // B3: a_s ready

    // ---- P3: masked softmax over 64 (first wave) ----
    if (tid < TQ_) {
      float av = a_s[tid];
      av = fminf(fmaxf(av, -15.f), 15.f) * mqv;
      float mx = av;
#pragma unroll
      for (int o = 1; o < 64; o <<= 1) mx = fmaxf(mx, __shfl_xor(mx, o));
      float e = __expf(av - mx) * mqv;
      float sm = e;
#pragma unroll
      for (int o = 1; o < 64; o <<= 1) sm += __shfl_xor(sm, o);
      alpha_s[tid] = __fdividef(e, sm + 1e-6f);
    }
    __syncthreads();   // B4: alpha ready

    // ---- P4qz: acc += alpha @ QZ column; pre complete ----
    {
      float av = alpha_s[lane];
#pragma unroll
      for (int t2 = 0; t2 < TQ_; ++t2)
        acc += lanebc(av, t2) * qz[t2];
      pre_s[n] = acc;
    }
    __syncthreads();   // B5: pre ready

    // ---- P5: LSTM pointwise + state update + output ----
    if (tid < H_) {
      float f  = pre_s[tid];
      float ig = pre_s[H_ + tid];
      float og = pre_s[2 * H_ + tid];
      float gg = pre_s[3 * H_ + tid];
      float c_old = c_s[tid], h_old = h_s[tid];
      float c1 = fast_sig(f) * c_old + fast_sig(ig) * fast_tanh(gg);
      c1 = c1 * mp + c_old * (1.f - mp);
      float h1 = fast_sig(og) * fast_tanh(c1);
      h1 = h1 * mp + h_old * (1.f - mp);
      c_s[tid] = c1;
      h_s[tid] = h1;
      out[(size_t)(bch * TP_ + t) * (2 * H_) + dir * H_ + tid] = h1 * mp;
      if (s == TP_ - 1)
        out[(size_t)B_ * TP_ * 2 * H_ + bch * (2 * H_) + dir * H_ + tid] = h1;
    }
    __syncthreads();   // B6: h_s/c_s stable for next step
  }
}

// ---------- host ----------
extern "C" void kernel_launch(void* const* d_in, const int* in_sizes, int n_in,
                              void* d_out, int out_size, void* d_ws, size_t ws_size,
                              hipStream_t stream) {
  const float* input_p = (const float*)d_in[0];
  const float* mask_p  = (const float*)d_in[1];
  const float* input_q = (const float*)d_in[2];
  const float* mask_q  = (const float*)d_in[3];
  const float* W_pr    = (const float*)d_in[4];
  const float* b_pr    = (const float*)d_in[5];
  const float* W_q     = (const float*)d_in[6];
  const float* b_q     = (const float*)d_in[7];
  const float* w_att   = (const float*)d_in[8];
  const float* b_match = (const float*)d_in[9];
  const float* W_lf    = (const float*)d_in[10];
  const float* b_lf    = (const float*)d_in[11];
  const float* W_lb    = (const float*)d_in[12];
  const float* b_lb    = (const float*)d_in[13];
  float* out = (float*)d_out;
  float* ws  = (float*)d_ws;

  // workspace layout (floats)
  float* Gq  = ws;                          // 2048*128    = 262144
  float* Gpx = Gq + 262144;                 // 8192*128    = 1048576
  float* XW  = Gpx + 1048576;               // 2*8192*512  = 8388608
  float* QZ  = XW + 8388608;                // 2*2048*512  = 2097152
  // total = 11,796,480 floats (~47.2 MB)

  dim3 blk(256);
  gemm_bias_kernel<<<dim3(2048 / 128, 128 / 128), blk, 0, stream>>>(input_q, W_q, b_q, Gq, 2048, 128, 256);
  gemm_bias_kernel<<<dim3(8192 / 128, 128 / 128), blk, 0, stream>>>(input_p, W_pr, b_pr, Gpx, 8192, 128, 256);
  gemm_bias_kernel<<<dim3(8192 / 128, 512 / 128), blk, 0, stream>>>(input_p, W_lf, b_lf, XW, 8192, 512, 256);
  gemm_bias_kernel<<<dim3(8192 / 128, 512 / 128), blk, 0, stream>>>(input_p, W_lb, b_lb, XW + (size_t)8192 * 512, 8192, 512, 256);
  gemm_bias_kernel<<<dim3(2048 / 128, 512 / 128), blk, 0, stream>>>(input_q, W_lf + 256 * 512, nullptr, QZ, 2048, 512, 256);
  gemm_bias_kernel<<<dim3(2048 / 128, 512 / 128), blk, 0, stream>>>(input_q, W_lb + 256 * 512, nullptr, QZ + (size_t)2048 * 512, 2048, 512, 256);

  // sequential bi-directional match-LSTM scan: 64 chains (32 batch x 2 dir)
  scan_kernel<<<64, 512, 0, stream>>>(Gq, Gpx, XW, QZ, W_pr, W_lf, W_lb,
                                      w_att, b_match, mask_p, mask_q, out);
}

// Round 7
// 2986.729 us; speedup vs baseline: 1.0009x; 1.0009x over previous
//
#include <hip/hip_runtime.h>
#include <hip/hip_bf16.h>

// Problem constants
#define B_   32
#define TP_  256
#define TQ_  64
#define D_   256
#define H_   128
#define G4_  512   // 4*H

// ---------- helpers ----------
__device__ __forceinline__ float lanebc(float v, int l) {
  // broadcast lane l of v to all lanes (uniform/literal l)
  return __int_as_float(__builtin_amdgcn_readlane(__float_as_int(v), l));
}
__device__ __forceinline__ float fast_tanh(float x) {
  x = fminf(fmaxf(x, -20.f), 20.f);
  float e = __expf(2.f * x);
  return __fdividef(e - 1.f, e + 1.f);
}
__device__ __forceinline__ float fast_sig(float x) {
  return __fdividef(1.f, 1.f + __expf(-x));
}

// ---------- tiled fp32 GEMM: C[M,N] = A[M,K] @ B[K,N] (+ bias[N]) ----------
// 128x128 tile, BK=8, 256 threads, 8x8 micro-tile.
__global__ __launch_bounds__(256)
void gemm_bias_kernel(const float* __restrict__ A, const float* __restrict__ Bm,
                      const float* __restrict__ bias, float* __restrict__ C,
                      int M, int N, int K)
{
  __shared__ float As[8][132];   // [k][m] transposed, +4 pad
  __shared__ float Bs[8][132];   // [k][n], +4 pad
  const int tid = threadIdx.x;
  const int tx = tid & 15;
  const int ty = tid >> 4;
  const int m0 = blockIdx.x * 128, n0 = blockIdx.y * 128;

  float acc[8][8];
#pragma unroll
  for (int i = 0; i < 8; ++i)
#pragma unroll
    for (int j = 0; j < 8; ++j) acc[i][j] = 0.f;

  const int am = tid >> 1, ak = (tid & 1) * 4;
  const int bk = tid >> 5, bn = (tid & 31) * 4;
  const float* Ap = A + (size_t)(m0 + am) * K + ak;
  const float* Bp = Bm + (size_t)bk * N + n0 + bn;

  for (int kt = 0; kt < K; kt += 8) {
    float4 a4 = *(const float4*)(Ap + kt);
    float4 b4 = *(const float4*)(Bp + (size_t)kt * N);
    __syncthreads();
    As[ak + 0][am] = a4.x; As[ak + 1][am] = a4.y;
    As[ak + 2][am] = a4.z; As[ak + 3][am] = a4.w;
    *(float4*)&Bs[bk][bn] = b4;
    __syncthreads();
#pragma unroll
    for (int k = 0; k < 8; ++k) {
      float4 a0 = *(const float4*)&As[k][ty * 8];
      float4 a1 = *(const float4*)&As[k][ty * 8 + 4];
      float4 b0 = *(const float4*)&Bs[k][tx * 8];
      float4 b1 = *(const float4*)&Bs[k][tx * 8 + 4];
      float av[8] = {a0.x, a0.y, a0.z, a0.w, a1.x, a1.y, a1.z, a1.w};
      float bv[8] = {b0.x, b0.y, b0.z, b0.w, b1.x, b1.y, b1.z, b1.w};
#pragma unroll
      for (int i = 0; i < 8; ++i)
#pragma unroll
        for (int j = 0; j < 8; ++j) acc[i][j] += av[i] * bv[j];
    }
  }

  float bb[8] = {0.f, 0.f, 0.f, 0.f, 0.f, 0.f, 0.f, 0.f};
  if (bias) {
    float4 b0 = *(const float4*)&bias[n0 + tx * 8];
    float4 b1 = *(const float4*)&bias[n0 + tx * 8 + 4];
    bb[0] = b0.x; bb[1] = b0.y; bb[2] = b0.z; bb[3] = b0.w;
    bb[4] = b1.x; bb[5] = b1.y; bb[6] = b1.z; bb[7] = b1.w;
  }
#pragma unroll
  for (int i = 0; i < 8; ++i) {
    float* cp = C + (size_t)(m0 + ty * 8 + i) * N + n0 + tx * 8;
    float4 o0, o1;
    o0.x = acc[i][0] + bb[0]; o0.y = acc[i][1] + bb[1];
    o0.z = acc[i][2] + bb[2]; o0.w = acc[i][3] + bb[3];
    o1.x = acc[i][4] + bb[4]; o1.y = acc[i][5] + bb[5];
    o1.z = acc[i][6] + bb[6]; o1.w = acc[i][7] + bb[7];
    *(float4*)(cp)     = o0;
    *(float4*)(cp + 4) = o1;
  }
}

// ---------- sequential scan: one block per (batch, dir) chain ----------
// 512 threads. amdgpu_waves_per_eu(2,2) pins occupancy target to 2 waves/EU ->
// VGPR cap 256. Pinned/thread: wreg[64] + wpr[32] + qz[64] + gqr[16] = 176 VGPR;
// Wh rows 64-127 in 128KB LDS (XOR-swizzled 16B granules, conflict-free).
// Per-step global traffic: XW row (2KB) + Gpx row (0.5KB) only.
// LESSON r5: launch_bounds(1024,4) -> VGPR_Count=64, full spill.
// LESSON r6: launch_bounds(512) default heuristic -> VGPR_Count=128, still spills
//            (needs ~216). This round: explicit waves_per_eu(2,2) -> expect 200-256.
__global__ __launch_bounds__(512) __attribute__((amdgpu_waves_per_eu(2, 2)))
void scan_kernel(const float* __restrict__ Gq,
                 const float* __restrict__ Gpx,
                 const float* __restrict__ XW,   // [2][B*TP*4H]
                 const float* __restrict__ QZ,   // [2][B*TQ*4H]
                 const float* __restrict__ W_pr, // (384,128)
                 const float* __restrict__ Wlf,  // (640,512)
                 const float* __restrict__ Wlb,  // (640,512)
                 const float* __restrict__ w_att,
                 const float* __restrict__ b_match,
                 const float* __restrict__ mask_p,
                 const float* __restrict__ mask_q,
                 float* __restrict__ out)        // states (B,TP,2H) then last (B,2H)
{
  const int tid  = threadIdx.x;
  const int lane = tid & 63;
  const int bch  = blockIdx.x >> 1;
  const int dir  = blockIdx.x & 1;
  const int n    = tid;          // pre column [0,512)   (P4)
  const int j1   = tid & 127;    // gpr column           (P1)
  const int kc   = tid >> 7;     // k-chunk [0,4)        (P1)
  const int t8   = tid >> 3;     // query timestep [0,64)(P2)
  const int k8   = tid & 7;      // j-slice [0,8)        (P2)

  // LDS: 128KB Wh-half + ~6.5KB working = ~134.5KB (< 160KB/CU)
  __shared__ float whlds[64 * 512];   // [n][granule g^(n&15)][4], rows 64..127
  __shared__ float h_s[H_], c_s[H_];
  __shared__ __align__(16) float gpr_s[H_];
  __shared__ float part_s[4][H_];
  __shared__ float a_s[TQ_];
  __shared__ float alpha_s[TQ_];
  __shared__ float pre_s[G4_];
  __shared__ __align__(16) float wa_s[H_];

  const float* Wl   = dir ? Wlb : Wlf;
  const float* XWd  = XW + (size_t)dir * (B_ * TP_ * G4_) + (size_t)bch * TP_ * G4_;
  const float* QZd  = QZ + (size_t)dir * (B_ * TQ_ * G4_) + (size_t)bch * TQ_ * G4_;
  const float* Gqb  = Gq + (size_t)bch * TQ_ * H_;
  const float* Gpxb = Gpx + (size_t)bch * TP_ * H_;
  const float* mpb  = mask_p + bch * TP_;
  const float  bm   = b_match[0];

  // ---- one-time staging ----
  // Wh LDS half: rows 64..127 of own column n. granule g=(k-64)>>2, sub=(k-64)&3,
  // physical slot g^(n&15) (16-lane clock groups cover all 16 slots -> conflict-free).
  for (int k = 0; k < 64; ++k) {
    float v = Wl[(size_t)(512 + 64 + k) * G4_ + n];     // coalesced across tid
    int g = k >> 2, sub = k & 3;
    whlds[(n << 6) + ((g ^ (n & 15)) << 2) + sub] = v;
  }
  // Wh register half: rows 0..63 of column n
  float wreg[64];
#pragma unroll
  for (int i = 0; i < 64; ++i)
    wreg[i] = Wl[(size_t)(512 + i) * G4_ + n];
  // Wpr_h: thread (kc,j1) holds rows kc*32..+32 of column j1
  float wpr[32];
#pragma unroll
  for (int i = 0; i < 32; ++i)
    wpr[i] = W_pr[(size_t)(256 + kc * 32 + i) * H_ + j1];
  // QZ column: qz[t2] = QZ[b,d][t2][n]
  float qz[TQ_];
#pragma unroll
  for (int t2 = 0; t2 < TQ_; ++t2)
    qz[t2] = QZd[(size_t)t2 * G4_ + n];
  // P2 per-thread Gq slice (16 regs); w_att shared via LDS
  float gqr[16];
#pragma unroll
  for (int i = 0; i < 16; ++i)
    gqr[i] = Gqb[t8 * H_ + k8 * 16 + i];
  if (tid < H_) wa_s[tid] = w_att[tid];
  float mqv = 0.f;
  if (tid < TQ_) mqv = mask_q[bch * TQ_ + tid];
  if (tid < H_) { h_s[tid] = 0.f; c_s[tid] = 0.f; }
  __syncthreads();

  const float* whbase = whlds + (size_t)(n << 6);
  const int    nx     = (n & 15);

  for (int s = 0; s < TP_; ++s) {
    const int t = dir ? (TP_ - 1 - s) : s;

    // per-step global prefetch (overlaps phase A)
    float xw_v = XWd[(size_t)t * G4_ + n];
    float gpx_v = 0.f, mp = 0.f;
    if (tid < H_) { gpx_v = Gpxb[t * H_ + tid]; mp = mpb[t]; }

    // stage h for wave broadcast
    float h2  = h_s[lane];
    float h2b = h_s[64 + lane];

    // ---- P1 partial: gpr[j1] over rows kc*32..+32 of Wpr_h ----
    {
      float accp = 0.f;
      float hsrc = (kc >= 2) ? h2b : h2;
      const int hb = (kc & 1) * 32;
#pragma unroll
      for (int i = 0; i < 32; ++i) accp += lanebc(hsrc, hb + i) * wpr[i];
      part_s[kc][j1] = accp;
    }
    // ---- P4h: acc = XW[n] + h @ Wh[:,n] (rows 0..63 regs, 64..127 LDS) ----
    float acc = xw_v;
#pragma unroll
    for (int i = 0; i < 64; ++i) acc += lanebc(h2, i) * wreg[i];
#pragma unroll
    for (int g = 0; g < 16; ++g) {
      const float4 w4 = *(const float4*)(whbase + ((g ^ nx) << 2));
      acc += lanebc(h2b, 4 * g + 0) * w4.x;
      acc += lanebc(h2b, 4 * g + 1) * w4.y;
      acc += lanebc(h2b, 4 * g + 2) * w4.z;
      acc += lanebc(h2b, 4 * g + 3) * w4.w;
    }
    __syncthreads();   // B1: part_s ready

    // ---- gpr combine ----
    if (tid < H_) {
      gpr_s[tid] = gpx_v + part_s[0][tid] + part_s[1][tid]
                 + part_s[2][tid] + part_s[3][tid];
    }
    __syncthreads();   // B2: gpr_s ready

    // ---- P2: a[t8] = bm + sum_j w_att[j]*tanh(gpr[j]+Gq[t8][j]), j=k8*16..+16 ----
    {
      const float4* gp  = (const float4*)&gpr_s[k8 * 16];
      const float4* wp4 = (const float4*)&wa_s[k8 * 16];
      float p = 0.f;
#pragma unroll
      for (int q = 0; q < 4; ++q) {
        const float4 g4 = gp[q];
        const float4 w4 = wp4[q];
        p += w4.x * fast_tanh(g4.x + gqr[q * 4 + 0]);
        p += w4.y * fast_tanh(g4.y + gqr[q * 4 + 1]);
        p += w4.z * fast_tanh(g4.z + gqr[q * 4 + 2]);
        p += w4.w * fast_tanh(g4.w + gqr[q * 4 + 3]);
      }
      p += __shfl_xor(p, 1);
      p += __shfl_xor(p, 2);
      p += __shfl_xor(p, 4);
      if (k8 == 0) a_s[t8] = p + bm;
    }
    __syncthreads();   // B3: a_s ready

    // ---- P3: masked softmax over 64 (first wave) ----
    if (tid < TQ_) {
      float av = a_s[tid];
      av = fminf(fmaxf(av, -15.f), 15.f) * mqv;
      float mx = av;
#pragma unroll
      for (int o = 1; o < 64; o <<= 1) mx = fmaxf(mx, __shfl_xor(mx, o));
      float e = __expf(av - mx) * mqv;
      float sm = e;
#pragma unroll
      for (int o = 1; o < 64; o <<= 1) sm += __shfl_xor(sm, o);
      alpha_s[tid] = __fdividef(e, sm + 1e-6f);
    }
    __syncthreads();   // B4: alpha ready

    // ---- P4qz: acc += alpha @ QZ column; pre complete ----
    {
      float av = alpha_s[lane];
#pragma unroll
      for (int t2 = 0; t2 < TQ_; ++t2)
        acc += lanebc(av, t2) * qz[t2];
      pre_s[n] = acc;
    }
    __syncthreads();   // B5: pre ready

    // ---- P5: LSTM pointwise + state update + output ----
    if (tid < H_) {
      float f  = pre_s[tid];
      float ig = pre_s[H_ + tid];
      float og = pre_s[2 * H_ + tid];
      float gg = pre_s[3 * H_ + tid];
      float c_old = c_s[tid], h_old = h_s[tid];
      float c1 = fast_sig(f) * c_old + fast_sig(ig) * fast_tanh(gg);
      c1 = c1 * mp + c_old * (1.f - mp);
      float h1 = fast_sig(og) * fast_tanh(c1);
      h1 = h1 * mp + h_old * (1.f - mp);
      c_s[tid] = c1;
      h_s[tid] = h1;
      out[(size_t)(bch * TP_ + t) * (2 * H_) + dir * H_ + tid] = h1 * mp;
      if (s == TP_ - 1)
        out[(size_t)B_ * TP_ * 2 * H_ + bch * (2 * H_) + dir * H_ + tid] = h1;
    }
    __syncthreads();   // B6: h_s/c_s stable for next step
  }
}

// ---------- host ----------
extern "C" void kernel_launch(void* const* d_in, const int* in_sizes, int n_in,
                              void* d_out, int out_size, void* d_ws, size_t ws_size,
                              hipStream_t stream) {
  const float* input_p = (const float*)d_in[0];
  const float* mask_p  = (const float*)d_in[1];
  const float* input_q = (const float*)d_in[2];
  const float* mask_q  = (const float*)d_in[3];
  const float* W_pr    = (const float*)d_in[4];
  const float* b_pr    = (const float*)d_in[5];
  const float* W_q     = (const float*)d_in[6];
  const float* b_q     = (const float*)d_in[7];
  const float* w_att   = (const float*)d_in[8];
  const float* b_match = (const float*)d_in[9];
  const float* W_lf    = (const float*)d_in[10];
  const float* b_lf    = (const float*)d_in[11];
  const float* W_lb    = (const float*)d_in[12];
  const float* b_lb    = (const float*)d_in[13];
  float* out = (float*)d_out;
  float* ws  = (float*)d_ws;

  // workspace layout (floats)
  float* Gq  = ws;                          // 2048*128    = 262144
  float* Gpx = Gq + 262144;                 // 8192*128    = 1048576
  float* XW  = Gpx + 1048576;               // 2*8192*512  = 8388608
  float* QZ  = XW + 8388608;                // 2*2048*512  = 2097152
  // total = 11,796,480 floats (~47.2 MB)

  dim3 blk(256);
  gemm_bias_kernel<<<dim3(2048 / 128, 128 / 128), blk, 0, stream>>>(input_q, W_q, b_q, Gq, 2048, 128, 256);
  gemm_bias_kernel<<<dim3(8192 / 128, 128 / 128), blk, 0, stream>>>(input_p, W_pr, b_pr, Gpx, 8192, 128, 256);
  gemm_bias_kernel<<<dim3(8192 / 128, 512 / 128), blk, 0, stream>>>(input_p, W_lf, b_lf, XW, 8192, 512, 256);
  gemm_bias_kernel<<<dim3(8192 / 128, 512 / 128), blk, 0, stream>>>(input_p, W_lb, b_lb, XW + (size_t)8192 * 512, 8192, 512, 256);
  gemm_bias_kernel<<<dim3(2048 / 128, 512 / 128), blk, 0, stream>>>(input_q, W_lf + 256 * 512, nullptr, QZ, 2048, 512, 256);
  gemm_bias_kernel<<<dim3(2048 / 128, 512 / 128), blk, 0, stream>>>(input_q, W_lb + 256 * 512, nullptr, QZ + (size_t)2048 * 512, 2048, 512, 256);

  // sequential bi-directional match-LSTM scan: 64 chains (32 batch x 2 dir)
  scan_kernel<<<64, 512, 0, stream>>>(Gq, Gpx, XW, QZ, W_pr, W_lf, W_lb,
                                      w_att, b_match, mask_p, mask_q, out);
}

// Round 9
// 1168.340 us; speedup vs baseline: 2.5588x; 2.5564x over previous
//
#include <hip/hip_runtime.h>
#include <hip/hip_bf16.h>
#include <hip/hip_fp16.h>

// Problem constants
#define B_   32
#define TP_  256
#define TQ_  64
#define D_   256
#define H_   128
#define G4_  512   // 4*H

// ---------- helpers ----------
__device__ __forceinline__ float lanebc(float v, int l) {
  return __int_as_float(__builtin_amdgcn_readlane(__float_as_int(v), l));
}
__device__ __forceinline__ unsigned rdlu(unsigned v, int l) {
  return (unsigned)__builtin_amdgcn_readlane((int)v, l);
}
__device__ __forceinline__ unsigned pk2(float lo, float hi) {
  __half2 h = __floats2half2_rn(lo, hi);
  return *reinterpret_cast<unsigned*>(&h);
}
// fp32 acc += dot(packed fp16 pair, packed fp16 pair)
__device__ __forceinline__ float dot2f(unsigned wu, unsigned hu, float acc) {
#if __has_builtin(__builtin_amdgcn_fdot2)
  typedef _Float16 h2v __attribute__((ext_vector_type(2)));
  h2v a = __builtin_bit_cast(h2v, wu);
  h2v b = __builtin_bit_cast(h2v, hu);
  return __builtin_amdgcn_fdot2(a, b, acc, false);
#else
  __half2 a = *reinterpret_cast<__half2*>(&wu);
  __half2 b = *reinterpret_cast<__half2*>(&hu);
  return acc + __low2float(a) * __low2float(b) + __high2float(a) * __high2float(b);
#endif
}
__device__ __forceinline__ float fast_tanh(float x) {
  x = fminf(fmaxf(x, -20.f), 20.f);
  float e = __expf(2.f * x);
  return __fdividef(e - 1.f, e + 1.f);
}
__device__ __forceinline__ float fast_sig(float x) {
  return __fdividef(1.f, 1.f + __expf(-x));
}

// ---------- tiled fp32 GEMM: C[M,N] = A[M,K] @ B[K,N] (+ bias[N]) ----------
// 128x128 tile, BK=8, 256 threads, 8x8 micro-tile. (unchanged from r2 baseline)
__global__ __launch_bounds__(256)
void gemm_bias_kernel(const float* __restrict__ A, const float* __restrict__ Bm,
                      const float* __restrict__ bias, float* __restrict__ C,
                      int M, int N, int K)
{
  __shared__ float As[8][132];
  __shared__ float Bs[8][132];
  const int tid = threadIdx.x;
  const int tx = tid & 15;
  const int ty = tid >> 4;
  const int m0 = blockIdx.x * 128, n0 = blockIdx.y * 128;

  float acc[8][8];
#pragma unroll
  for (int i = 0; i < 8; ++i)
#pragma unroll
    for (int j = 0; j < 8; ++j) acc[i][j] = 0.f;

  const int am = tid >> 1, ak = (tid & 1) * 4;
  const int bk = tid >> 5, bn = (tid & 31) * 4;
  const float* Ap = A + (size_t)(m0 + am) * K + ak;
  const float* Bp = Bm + (size_t)bk * N + n0 + bn;

  for (int kt = 0; kt < K; kt += 8) {
    float4 a4 = *(const float4*)(Ap + kt);
    float4 b4 = *(const float4*)(Bp + (size_t)kt * N);
    __syncthreads();
    As[ak + 0][am] = a4.x; As[ak + 1][am] = a4.y;
    As[ak + 2][am] = a4.z; As[ak + 3][am] = a4.w;
    *(float4*)&Bs[bk][bn] = b4;
    __syncthreads();
#pragma unroll
    for (int k = 0; k < 8; ++k) {
      float4 a0 = *(const float4*)&As[k][ty * 8];
      float4 a1 = *(const float4*)&As[k][ty * 8 + 4];
      float4 b0 = *(const float4*)&Bs[k][tx * 8];
      float4 b1 = *(const float4*)&Bs[k][tx * 8 + 4];
      float av[8] = {a0.x, a0.y, a0.z, a0.w, a1.x, a1.y, a1.z, a1.w};
      float bv[8] = {b0.x, b0.y, b0.z, b0.w, b1.x, b1.y, b1.z, b1.w};
#pragma unroll
      for (int i = 0; i < 8; ++i)
#pragma unroll
        for (int j = 0; j < 8; ++j) acc[i][j] += av[i] * bv[j];
    }
  }

  float bb[8] = {0.f, 0.f, 0.f, 0.f, 0.f, 0.f, 0.f, 0.f};
  if (bias) {
    float4 b0 = *(const float4*)&bias[n0 + tx * 8];
    float4 b1 = *(const float4*)&bias[n0 + tx * 8 + 4];
    bb[0] = b0.x; bb[1] = b0.y; bb[2] = b0.z; bb[3] = b0.w;
    bb[4] = b1.x; bb[5] = b1.y; bb[6] = b1.z; bb[7] = b1.w;
  }
#pragma unroll
  for (int i = 0; i < 8; ++i) {
    float* cp = C + (size_t)(m0 + ty * 8 + i) * N + n0 + tx * 8;
    float4 o0, o1;
    o0.x = acc[i][0] + bb[0]; o0.y = acc[i][1] + bb[1];
    o0.z = acc[i][2] + bb[2]; o0.w = acc[i][3] + bb[3];
    o1.x = acc[i][4] + bb[4]; o1.y = acc[i][5] + bb[5];
    o1.z = acc[i][6] + bb[6]; o1.w = acc[i][7] + bb[7];
    *(float4*)(cp)     = o0;
    *(float4*)(cp + 4) = o1;
  }
}

// ---------- sequential scan: one block per (batch, dir) chain ----------
// 512 threads. REDESIGN (r8, resubmitted r9 after infra timeout): everything
// fits under the 128-VGPR cap the backend enforces (r5/r6/r7 all spilled).
//  * Wh as packed fp16, column-major, FULLY LDS-resident (128KB), XOR-granule
//    swizzled -> conflict-free ds_read_b128.
//  * All h-dots via v_dot2_f32_f16 (fp32 accumulate): Wh, Wpr_h, alpha@QZ.
//  * Pinned regs: wpr_pk[16] + qz_pk[32] + gqr[16] = 64; live ~35 -> ~100 VGPR.
//  * h/c state in per-thread registers (tid<128); packed-h pairs in hpk_s[64].
// Per-step global traffic: XW row (2KB) + Gpx row (0.5KB) only.
__global__ __launch_bounds__(512)
void scan_kernel(const float* __restrict__ Gq,
                 const float* __restrict__ Gpx,
                 const float* __restrict__ XW,   // [2][B*TP*4H]
                 const float* __restrict__ QZ,   // [2][B*TQ*4H]
                 const float* __restrict__ W_pr, // (384,128)
                 const float* __restrict__ Wlf,  // (640,512)
                 const float* __restrict__ Wlb,  // (640,512)
                 const float* __restrict__ w_att,
                 const float* __restrict__ b_match,
                 const float* __restrict__ mask_p,
                 const float* __restrict__ mask_q,
                 float* __restrict__ out)        // states (B,TP,2H) then last (B,2H)
{
  const int tid  = threadIdx.x;
  const int lane = tid & 63;
  const int bch  = blockIdx.x >> 1;
  const int dir  = blockIdx.x & 1;
  const int n    = tid;          // pre column [0,512)   (P4)
  const int j1   = tid & 127;    // gpr column           (P1)
  const int kc   = tid >> 7;     // k-chunk [0,4)        (P1)
  const int t8   = tid >> 3;     // query timestep [0,64)(P2)
  const int k8   = tid & 7;      // j-slice [0,8)        (P2)
  const int nx   = tid & 15;

  // LDS: 128KB Wh(fp16) + ~6KB working = ~134KB (< 160KB/CU)
  __shared__ unsigned whlds[G4_ * 64];  // [n][pg][4] u32; pair p: g=p>>2,j=p&3, pg=g^(n&15)
  __shared__ __align__(16) float gpr_s[H_];
  __shared__ float part_s[4][H_];
  __shared__ float a_s[TQ_];
  __shared__ unsigned alpha_pk_s[TQ_ / 2];
  __shared__ unsigned hpk_s[H_ / 2];
  __shared__ float pre_s[G4_];
  __shared__ __align__(16) float wa_s[H_];

  const float* Wl   = dir ? Wlb : Wlf;
  const float* XWd  = XW + (size_t)dir * (B_ * TP_ * G4_) + (size_t)bch * TP_ * G4_;
  const float* QZd  = QZ + (size_t)dir * (B_ * TQ_ * G4_) + (size_t)bch * TQ_ * G4_;
  const float* Gqb  = Gq + (size_t)bch * TQ_ * H_;
  const float* Gpxb = Gpx + (size_t)bch * TP_ * H_;
  const float* mpb  = mask_p + bch * TP_;
  const float  bm   = b_match[0];

  // ---- one-time staging (fp32 -> packed fp16, RTN) ----
  // Wh column n, pair p (= h rows 2p,2p+1). Coalesced across threads per row.
  for (int p = 0; p < 64; ++p) {
    float lo = Wl[(size_t)(512 + 2 * p) * G4_ + n];
    float hi = Wl[(size_t)(512 + 2 * p + 1) * G4_ + n];
    int g = p >> 2, j = p & 3;
    whlds[(n << 6) + ((g ^ nx) << 2) + j] = pk2(lo, hi);
  }
  // Wpr_h: thread (kc,j1) holds pairs kc*16..+16 of column j1
  unsigned wpr_pk[16];
#pragma unroll
  for (int i = 0; i < 16; ++i)
    wpr_pk[i] = pk2(W_pr[(size_t)(256 + kc * 32 + 2 * i) * H_ + j1],
                    W_pr[(size_t)(256 + kc * 32 + 2 * i + 1) * H_ + j1]);
  // QZ column n, packed pairs over t2
  unsigned qz_pk[32];
#pragma unroll
  for (int i = 0; i < 32; ++i)
    qz_pk[i] = pk2(QZd[(size_t)(2 * i) * G4_ + n],
                   QZd[(size_t)(2 * i + 1) * G4_ + n]);
  // P2 per-thread Gq slice; w_att via LDS
  float gqr[16];
#pragma unroll
  for (int i = 0; i < 16; ++i)
    gqr[i] = Gqb[t8 * H_ + k8 * 16 + i];
  if (tid < H_) wa_s[tid] = w_att[tid];
  float mqv = 0.f;
  if (tid < TQ_) mqv = mask_q[bch * TQ_ + tid];
  if (tid < H_ / 2) hpk_s[tid] = 0u;
  // per-thread LSTM state (tid<128 owns element tid)
  float hstate = 0.f, cstate = 0.f;
  __syncthreads();

  const unsigned* whbase = whlds + (n << 6);

  for (int s = 0; s < TP_; ++s) {
    const int t = dir ? (TP_ - 1 - s) : s;

    // per-step global prefetch (overlaps phase A)
    float xw_v = XWd[(size_t)t * G4_ + n];
    float gpx_v = 0.f, mp = 0.f;
    if (tid < H_) { gpx_v = Gpxb[t * H_ + tid]; mp = mpb[t]; }

    // packed h pairs for wave broadcast
    unsigned hpkv = hpk_s[lane];

    // ---- P1 partial: gpr[j1] over pairs kc*16..+16 of Wpr_h ----
    {
      float accp = 0.f;
#pragma unroll
      for (int i = 0; i < 16; ++i)
        accp = dot2f(wpr_pk[i], rdlu(hpkv, kc * 16 + i), accp);
      part_s[kc][j1] = accp;
    }
    // ---- P4h: acc = XW[n] + h @ Wh[:,n] (packed fp16 LDS, dot2) ----
    float acc = xw_v;
#pragma unroll
    for (int g = 0; g < 16; ++g) {
      const uint4 w4 = *(const uint4*)(whbase + ((g ^ nx) << 2));
      acc = dot2f(w4.x, rdlu(hpkv, 4 * g + 0), acc);
      acc = dot2f(w4.y, rdlu(hpkv, 4 * g + 1), acc);
      acc = dot2f(w4.z, rdlu(hpkv, 4 * g + 2), acc);
      acc = dot2f(w4.w, rdlu(hpkv, 4 * g + 3), acc);
    }
    __syncthreads();   // B1: part_s ready

    // ---- gpr combine ----
    if (tid < H_) {
      gpr_s[tid] = gpx_v + part_s[0][tid] + part_s[1][tid]
                 + part_s[2][tid] + part_s[3][tid];
    }
    __syncthreads();   // B2: gpr_s ready

    // ---- P2: a[t8] = bm + sum_j w_att[j]*tanh(gpr[j]+Gq[t8][j]), j=k8*16..+16 ----
    {
      const float4* gp  = (const float4*)&gpr_s[k8 * 16];
      const float4* wp4 = (const float4*)&wa_s[k8 * 16];
      float p = 0.f;
#pragma unroll
      for (int q = 0; q < 4; ++q) {
        const float4 g4 = gp[q];
        const float4 w4 = wp4[q];
        p += w4.x * fast_tanh(g4.x + gqr[q * 4 + 0]);
        p += w4.y * fast_tanh(g4.y + gqr[q * 4 + 1]);
        p += w4.z * fast_tanh(g4.z + gqr[q * 4 + 2]);
        p += w4.w * fast_tanh(g4.w + gqr[q * 4 + 3]);
      }
      p += __shfl_xor(p, 1);
      p += __shfl_xor(p, 2);
      p += __shfl_xor(p, 4);
      if (k8 == 0) a_s[t8] = p + bm;
    }
    __syncthreads();   // B3: a_s ready

    // ---- P3: masked softmax over 64 (first wave) + pack alpha pairs ----
    if (tid < TQ_) {
      float av = a_s[tid];
      av = fminf(fmaxf(av, -15.f), 15.f) * mqv;
      float mx = av;
#pragma unroll
      for (int o = 1; o < 64; o <<= 1) mx = fmaxf(mx, __shfl_xor(mx, o));
      float e = __expf(av - mx) * mqv;
      float sm = e;
#pragma unroll
      for (int o = 1; o < 64; o <<= 1) sm += __shfl_xor(sm, o);
      float al = __fdividef(e, sm + 1e-6f);
      float al_hi = __shfl_xor(al, 1);
      if ((lane & 1) == 0) alpha_pk_s[lane >> 1] = pk2(al, al_hi);
    }
    __syncthreads();   // B4: alpha ready

    // ---- P4qz: acc += alpha @ QZ column (packed dot2); pre complete ----
    {
      unsigned apv = alpha_pk_s[lane & 31];
#pragma unroll
      for (int i = 0; i < 32; ++i)
        acc = dot2f(qz_pk[i], rdlu(apv, i), acc);
      pre_s[n] = acc;
    }
    __syncthreads();   // B5: pre ready

    // ---- P5: LSTM pointwise + state update + output (+ pack h pairs) ----
    if (tid < H_) {
      float f  = pre_s[tid];
      float ig = pre_s[H_ + tid];
      float og = pre_s[2 * H_ + tid];
      float gg = pre_s[3 * H_ + tid];
      float c1 = fast_sig(f) * cstate + fast_sig(ig) * fast_tanh(gg);
      c1 = c1 * mp + cstate * (1.f - mp);
      float h1 = fast_sig(og) * fast_tanh(c1);
      h1 = h1 * mp + hstate * (1.f - mp);
      cstate = c1;
      hstate = h1;
      out[(size_t)(bch * TP_ + t) * (2 * H_) + dir * H_ + tid] = h1 * mp;
      if (s == TP_ - 1)
        out[(size_t)B_ * TP_ * 2 * H_ + bch * (2 * H_) + dir * H_ + tid] = h1;
      float h_hi = __shfl_xor(h1, 1);
      if ((tid & 1) == 0) hpk_s[tid >> 1] = pk2(h1, h_hi);
    }
    __syncthreads();   // B6: hpk_s stable for next step
  }
}

// ---------- host ----------
extern "C" void kernel_launch(void* const* d_in, const int* in_sizes, int n_in,
                              void* d_out, int out_size, void* d_ws, size_t ws_size,
                              hipStream_t stream) {
  const float* input_p = (const float*)d_in[0];
  const float* mask_p  = (const float*)d_in[1];
  const float* input_q = (const float*)d_in[2];
  const float* mask_q  = (const float*)d_in[3];
  const float* W_pr    = (const float*)d_in[4];
  const float* b_pr    = (const float*)d_in[5];
  const float* W_q     = (const float*)d_in[6];
  const float* b_q     = (const float*)d_in[7];
  const float* w_att   = (const float*)d_in[8];
  const float* b_match = (const float*)d_in[9];
  const float* W_lf    = (const float*)d_in[10];
  const float* b_lf    = (const float*)d_in[11];
  const float* W_lb    = (const float*)d_in[12];
  const float* b_lb    = (const float*)d_in[13];
  float* out = (float*)d_out;
  float* ws  = (float*)d_ws;

  // workspace layout (floats)
  float* Gq  = ws;                          // 2048*128    = 262144
  float* Gpx = Gq + 262144;                 // 8192*128    = 1048576
  float* XW  = Gpx + 1048576;               // 2*8192*512  = 8388608
  float* QZ  = XW + 8388608;                // 2*2048*512  = 2097152
  // total = 11,796,480 floats (~47.2 MB)

  dim3 blk(256);
  gemm_bias_kernel<<<dim3(2048 / 128, 128 / 128), blk, 0, stream>>>(input_q, W_q, b_q, Gq, 2048, 128, 256);
  gemm_bias_kernel<<<dim3(8192 / 128, 128 / 128), blk, 0, stream>>>(input_p, W_pr, b_pr, Gpx, 8192, 128, 256);
  gemm_bias_kernel<<<dim3(8192 / 128, 512 / 128), blk, 0, stream>>>(input_p, W_lf, b_lf, XW, 8192, 512, 256);
  gemm_bias_kernel<<<dim3(8192 / 128, 512 / 128), blk, 0, stream>>>(input_p, W_lb, b_lb, XW + (size_t)8192 * 512, 8192, 512, 256);
  gemm_bias_kernel<<<dim3(2048 / 128, 512 / 128), blk, 0, stream>>>(input_q, W_lf + 256 * 512, nullptr, QZ, 2048, 512, 256);
  gemm_bias_kernel<<<dim3(2048 / 128, 512 / 128), blk, 0, stream>>>(input_q, W_lb + 256 * 512, nullptr, QZ + (size_t)2048 * 512, 2048, 512, 256);

  // sequential bi-directional match-LSTM scan: 64 chains (32 batch x 2 dir)
  scan_kernel<<<64, 512, 0, stream>>>(Gq, Gpx, XW, QZ, W_pr, W_lf, W_lb,
                                      w_att, b_match, mask_p, mask_q, out);
}